// Round 12
// baseline (10136.450 us; speedup 1.0000x reference)
//
#include <hip/hip_runtime.h>

typedef unsigned int u32;
typedef unsigned long long u64;
typedef float v2f __attribute__((ext_vector_type(2)));

// ---------------------------------------------------------------------------
// helpers
// ---------------------------------------------------------------------------
__device__ __forceinline__ u64 shflx64(u64 v, int m) {
  int lo = __shfl_xor((int)(u32)v, m, 64);
  int hi = __shfl_xor((int)(u32)(v >> 32), m, 64);
  return ((u64)(u32)hi << 32) | (u32)lo;
}
__device__ __forceinline__ u64 maxu64(u64 a, u64 b) { return a > b ? a : b; }

__device__ __forceinline__ float boxlb(float cx, float cy, float cz,
                                       float nx, float xx, float ny, float xy,
                                       float nz, float xz) {
  float gx = fmaxf(fmaxf(nx - cx, cx - xx), 0.0f);
  float gy = fmaxf(fmaxf(ny - cy, cy - xy), 0.0f);
  float gz = fmaxf(fmaxf(nz - cz, cz - xz), 0.0f);
  return gx * gx + gy * gy + gz * gz;
}

// ---------------------------------------------------------------------------
// Kernel 0: Morton bucket sort (counting sort, 2048 buckets, 4/4/3 bits).
// Exports bucket end offsets + grid metadata; initializes the fps progress
// counters to -1 (stream-ordered before the mega kernel).
// ---------------------------------------------------------------------------
#define SORT_T 1024

__global__ __launch_bounds__(SORT_T) void k_sort(const float* __restrict__ clouds,
                                                 u32* __restrict__ order,
                                                 u32* __restrict__ bends,
                                                 float* __restrict__ meta,
                                                 int* __restrict__ progress, int N) {
  const int b = blockIdx.x, tid = threadIdx.x;
  const float* xs = clouds + (size_t)b * 4 * N;
  const float* ys = xs + N;
  const float* zs = ys + N;

  __shared__ u32 hist[2048];
  __shared__ u32 base[2048];
  __shared__ float red[96];
  __shared__ u32 wsum[16];

  if (tid == 0) progress[b] = -1;

  float mnx = 3.4e38f, mxx = -3.4e38f, mny = 3.4e38f, mxy = -3.4e38f,
        mnz = 3.4e38f, mxz = -3.4e38f;
  for (int i = tid; i < N; i += SORT_T) {
    float x = xs[i], y = ys[i], z = zs[i];
    mnx = fminf(mnx, x); mxx = fmaxf(mxx, x);
    mny = fminf(mny, y); mxy = fmaxf(mxy, y);
    mnz = fminf(mnz, z); mxz = fmaxf(mxz, z);
  }
#pragma unroll
  for (int s = 1; s < 64; s <<= 1) {
    mnx = fminf(mnx, __shfl_xor(mnx, s, 64)); mxx = fmaxf(mxx, __shfl_xor(mxx, s, 64));
    mny = fminf(mny, __shfl_xor(mny, s, 64)); mxy = fmaxf(mxy, __shfl_xor(mxy, s, 64));
    mnz = fminf(mnz, __shfl_xor(mnz, s, 64)); mxz = fmaxf(mxz, __shfl_xor(mxz, s, 64));
  }
  const int wv = tid >> 6, ln = tid & 63;
  if (ln == 0) {
    red[wv * 6 + 0] = mnx; red[wv * 6 + 1] = mxx;
    red[wv * 6 + 2] = mny; red[wv * 6 + 3] = mxy;
    red[wv * 6 + 4] = mnz; red[wv * 6 + 5] = mxz;
  }
  hist[tid] = 0u; hist[tid + 1024] = 0u;
  __syncthreads();
  float bmnx = red[0], bmxx = red[1], bmny = red[2], bmxy = red[3],
        bmnz = red[4], bmxz = red[5];
#pragma unroll
  for (int w = 1; w < 16; ++w) {
    bmnx = fminf(bmnx, red[w * 6 + 0]); bmxx = fmaxf(bmxx, red[w * 6 + 1]);
    bmny = fminf(bmny, red[w * 6 + 2]); bmxy = fmaxf(bmxy, red[w * 6 + 3]);
    bmnz = fminf(bmnz, red[w * 6 + 4]); bmxz = fmaxf(bmxz, red[w * 6 + 5]);
  }
  const float sx = 16.0f / fmaxf(bmxx - bmnx, 1e-9f);
  const float sy = 16.0f / fmaxf(bmxy - bmny, 1e-9f);
  const float sz = 8.0f / fmaxf(bmxz - bmnz, 1e-9f);
  if (tid == 0) {
    meta[b * 8 + 0] = bmnx; meta[b * 8 + 1] = bmny; meta[b * 8 + 2] = bmnz;
    meta[b * 8 + 3] = fmaxf(bmxx - bmnx, 1e-9f) / 16.0f;
    meta[b * 8 + 4] = fmaxf(bmxy - bmny, 1e-9f) / 16.0f;
    meta[b * 8 + 5] = fmaxf(bmxz - bmnz, 1e-9f) / 8.0f;
  }

  for (int i = tid; i < N; i += SORT_T) {
    int qx = min(15, max(0, (int)((xs[i] - bmnx) * sx)));
    int qy = min(15, max(0, (int)((ys[i] - bmny) * sy)));
    int qz = min(7, max(0, (int)((zs[i] - bmnz) * sz)));
    u32 m = 0; int sh = 0;
#pragma unroll
    for (int bit = 0; bit < 4; ++bit) {
      m |= ((u32)((qx >> bit) & 1)) << sh++;
      m |= ((u32)((qy >> bit) & 1)) << sh++;
      if (bit < 3) m |= ((u32)((qz >> bit) & 1)) << sh++;
    }
    atomicAdd(&hist[m], 1u);
  }
  __syncthreads();

  u32 s0 = hist[2 * tid], s1 = hist[2 * tid + 1];
  u32 ts = s0 + s1;
  u32 x = ts;
#pragma unroll
  for (int d = 1; d < 64; d <<= 1) {
    u32 o = (u32)__shfl_up((int)x, d, 64);
    if (ln >= d) x += o;
  }
  if (ln == 63) wsum[wv] = x;
  __syncthreads();
  u32 wpre = 0;
#pragma unroll
  for (int w = 0; w < 16; ++w) wpre += (w < wv) ? wsum[w] : 0u;
  u32 tbase = wpre + x - ts;
  base[2 * tid] = tbase;
  base[2 * tid + 1] = tbase + s0;
  __syncthreads();

  for (int i = tid; i < N; i += SORT_T) {
    int qx = min(15, max(0, (int)((xs[i] - bmnx) * sx)));
    int qy = min(15, max(0, (int)((ys[i] - bmny) * sy)));
    int qz = min(7, max(0, (int)((zs[i] - bmnz) * sz)));
    u32 m = 0; int sh = 0;
#pragma unroll
    for (int bit = 0; bit < 4; ++bit) {
      m |= ((u32)((qx >> bit) & 1)) << sh++;
      m |= ((u32)((qy >> bit) & 1)) << sh++;
      if (bit < 3) m |= ((u32)((qz >> bit) & 1)) << sh++;
    }
    u32 pos = atomicAdd(&base[m], 1u);
    order[(size_t)b * N + pos] = (u32)i;
  }
  __syncthreads();
  for (int m = tid; m < 2048; m += SORT_T)
    bends[(size_t)b * 2048 + m] = base[m];
}

// ---------------------------------------------------------------------------
// Mega kernel: blocks 0..1 run the exact round-11 FPS (publishing a progress
// counter every 16 picks, device-scope release); blocks 2..239 are workers
// that spin-wait per keypoint-pair then run knn + fused pools. Co-residency
// is guaranteed by capacity: 240 blocks <= 256 CUs, each block schedulable
// (16 waves, ~55 KB LDS, VGPR <= 128 via launch bounds) -> no deadlock
// regardless of dispatch order. All selection math bitwise-identical to the
// round-11 kernels; pool arithmetic keeps the exact per-element fmaf k-order.
// ---------------------------------------------------------------------------
#define MEGA_T 1024
#define NWORK 238
#define CCAP 512
#define BCAP 192
#define SENTINEL (((u64)0x7F7FFFFFu) << 32)

template <int M>
__device__ __forceinline__ void pool_body(
    int tid, int kp, const u64* gsrt,
    const float* __restrict__ w1, const float* __restrict__ w2,
    float R2s, int colOff,
    const float* xs, const float* ys, const float* zs, const float* fs,
    float kx, float ky, float kz,
    float* w1l, float* gx, float* gy, float* gz, float* gf,
    float* h1l, float* w2l, u32* pm, float* __restrict__ pooled) {
  constexpr int R = M / 4;
  if (tid < 512) w1l[tid] = w1[tid];
  if (tid < 256) pm[tid] = 0u;
  if (tid < M) {
    u64 sl = gsrt[tid];
    float d2 = __uint_as_float((u32)(sl >> 32));
    u32 idx = (u32)sl;
    float vx = 0.f, vy = 0.f, vz = 0.f, vf = 0.f;
    if (d2 < R2s) {
      vx = xs[idx] - kx; vy = ys[idx] - ky; vz = zs[idx] - kz; vf = fs[idx];
    }
    gx[tid] = vx; gy[tid] = vy; gz[tid] = vz; gf[tid] = vf;
  }
  __syncthreads();
  // layer1 (identical fmaf sequence to the standalone k_pool)
  {
    const int c = tid & 127;
    const int r0 = tid >> 7;  // 0..7
#pragma unroll
    for (int q = 0; q < M / 8; ++q) {
      int r = r0 + 8 * q;
      float h = fmaf(gf[r], w1l[384 + c],
                fmaf(gz[r], w1l[256 + c],
                fmaf(gy[r], w1l[128 + c], gx[r] * w1l[c])));
      h1l[r * 132 + c] = fmaxf(h, 0.0f);
    }
  }
  const int rt = tid >> 8;   // 4 row tiles of R rows
  const int cg = tid & 255;  // 1 col each
  float acc[R];
#pragma unroll
  for (int r = 0; r < R; ++r) acc[r] = 0.0f;
  for (int kt = 0; kt < 8; ++kt) {
    __syncthreads();
    for (int q = tid; q < 16 * 256; q += MEGA_T)
      w2l[q] = w2[(size_t)(kt * 16 + (q >> 8)) * 256 + (q & 255)];
    __syncthreads();
    for (int k = 0; k < 16; k += 4) {
      float w0 = w2l[(k + 0) * 256 + cg];
      float w1v = w2l[(k + 1) * 256 + cg];
      float w2v = w2l[(k + 2) * 256 + cg];
      float w3v = w2l[(k + 3) * 256 + cg];
#pragma unroll
      for (int r = 0; r < R; ++r) {
        float4 hv = *reinterpret_cast<const float4*>(
            &h1l[(rt * R + r) * 132 + kt * 16 + k]);
        acc[r] = fmaf(hv.w, w3v, fmaf(hv.z, w2v,
                 fmaf(hv.y, w1v, fmaf(hv.x, w0, acc[r]))));
      }
    }
  }
  float mx = 0.0f;
#pragma unroll
  for (int r = 0; r < R; ++r) mx = fmaxf(mx, acc[r]);
  atomicMax(&pm[cg], __float_as_uint(mx));
  __syncthreads();
  if (tid < 256) pooled[(size_t)kp * 512 + colOff + tid] = __uint_as_float(pm[tid]);
  __syncthreads();
}

__global__ __launch_bounds__(MEGA_T, 4) void k_mega(
    const float* __restrict__ clouds, const u32* __restrict__ order,
    const u32* __restrict__ bends, const float* __restrict__ meta,
    const float* __restrict__ w1a, const float* __restrict__ w2a,
    const float* __restrict__ w1b, const float* __restrict__ w2b,
    float* __restrict__ keyp, float* __restrict__ pooled,
    float* __restrict__ out, int* __restrict__ progress,
    int N, int K, int nPairs, float r2a, float r2b) {
  __shared__ u64 fslots[2][16];
  __shared__ u32 lends[2048];
  __shared__ u64 cand[2][CCAP];
  __shared__ u32 blist[2][BCAP];
  __shared__ int cnt[2], bcnt[2], readyf;
  __shared__ u64 gsort[2][32];
  __shared__ float w1l[512];
  __shared__ float sgx[32], sgy[32], sgz[32], sgf[32];
  __shared__ float h1l[32 * 132];
  __shared__ float w2l[16 * 256];
  __shared__ u32 pm[256];

  const int tid = threadIdx.x;

  if (blockIdx.x < 2) {
    // ------------------------- FPS (round-11 anchor + publish) -------------
    const int b = blockIdx.x;
    const float* xs = clouds + (size_t)b * 4 * N;
    const float* ys = xs + N;
    const float* zs = ys + N;

    int oid[16];
    v2f px2[8], py2[8], pz2[8], dd2[8];
#pragma unroll
    for (int j = 0; j < 16; ++j) oid[j] = (int)order[(size_t)b * N + tid * 16 + j];
#pragma unroll
    for (int i = 0; i < 8; ++i) {
      px2[i].x = xs[oid[2 * i]]; px2[i].y = xs[oid[2 * i + 1]];
      py2[i].x = ys[oid[2 * i]]; py2[i].y = ys[oid[2 * i + 1]];
      pz2[i].x = zs[oid[2 * i]]; pz2[i].y = zs[oid[2 * i + 1]];
      dd2[i].x = 1e10f; dd2[i].y = 1e10f;
    }
    float bnx = px2[0].x, bxx = px2[0].x, bny = py2[0].x, bxy = py2[0].x,
          bnz = pz2[0].x, bxz = pz2[0].x;
#pragma unroll
    for (int i = 0; i < 8; ++i) {
      bnx = fminf(bnx, fminf(px2[i].x, px2[i].y));
      bxx = fmaxf(bxx, fmaxf(px2[i].x, px2[i].y));
      bny = fminf(bny, fminf(py2[i].x, py2[i].y));
      bxy = fmaxf(bxy, fmaxf(py2[i].x, py2[i].y));
      bnz = fminf(bnz, fminf(pz2[i].x, pz2[i].y));
      bxz = fmaxf(bxz, fmaxf(pz2[i].x, pz2[i].y));
    }
    float wnx = bnx, wxx = bxx, wny = bny, wxy = bxy, wnz = bnz, wxz = bxz;
#pragma unroll
    for (int s = 1; s < 64; s <<= 1) {
      wnx = fminf(wnx, __shfl_xor(wnx, s, 64)); wxx = fmaxf(wxx, __shfl_xor(wxx, s, 64));
      wny = fminf(wny, __shfl_xor(wny, s, 64)); wxy = fmaxf(wxy, __shfl_xor(wxy, s, 64));
      wnz = fminf(wnz, __shfl_xor(wnz, s, 64)); wxz = fmaxf(wxz, __shfl_xor(wxz, s, 64));
    }

    const int wv = tid >> 6, ln = tid & 63;
    u64 ckey = 0, wkey = 0;
    float cmax = 1e10f, wmax = 1e10f;
    float cx = xs[0], cy = ys[0], cz = zs[0];
    if (tid == 0) {
      float* kb = keyp + (size_t)b * K * 3;
      kb[0] = cx; kb[1] = cy; kb[2] = cz;
    }

    for (int t = 1; t < K; ++t) {
      const int par = t & 1;
      float gx = fmaxf(fmaxf(wnx - cx, cx - wxx), 0.0f);
      float gy = fmaxf(fmaxf(wny - cy, cy - wxy), 0.0f);
      float gz = fmaxf(fmaxf(wnz - cz, cz - wxz), 0.0f);
      float lbw = gx * gx + gy * gy + gz * gz;
      if (lbw <= wmax * 1.00001f) {
        float hx = fmaxf(fmaxf(bnx - cx, cx - bxx), 0.0f);
        float hy = fmaxf(fmaxf(bny - cy, cy - bxy), 0.0f);
        float hz = fmaxf(fmaxf(bnz - cz, cz - bxz), 0.0f);
        float lbt = hx * hx + hy * hy + hz * hz;
        if (lbt <= cmax * 1.00001f) {
          float m = 0.0f;
          {
#pragma clang fp contract(off)
            const v2f c2x = {cx, cx}, c2y = {cy, cy}, c2z = {cz, cz};
#pragma unroll
            for (int i = 0; i < 8; ++i) {
              v2f dx = px2[i] - c2x;
              v2f dy = py2[i] - c2y;
              v2f dz = pz2[i] - c2z;
              v2f d = (dx * dx + dy * dy) + dz * dz;
              float n0 = fminf(dd2[i].x, d.x);
              float n1 = fminf(dd2[i].y, d.y);
              dd2[i].x = n0; dd2[i].y = n1;
              m = fmaxf(m, fmaxf(n0, n1));
            }
          }
          u32 mi = 0xFFFFFFFFu;
#pragma unroll
          for (int i = 0; i < 8; ++i) {
            if (dd2[i].x == m) mi = min(mi, (u32)oid[2 * i]);
            if (dd2[i].y == m) mi = min(mi, (u32)oid[2 * i + 1]);
          }
          cmax = m;
          ckey = ((u64)__float_as_uint(m) << 32) | (u64)(u32)(~mi);
        }
        u64 wk = ckey;
#pragma unroll
        for (int s = 1; s < 64; s <<= 1) wk = maxu64(wk, shflx64(wk, s));
        wkey = wk;
        wmax = __uint_as_float((u32)(wkey >> 32));
      }
      if (ln == 0) fslots[par][wv] = wkey;
      __syncthreads();
      u64 sk = fslots[par][ln & 15];
#pragma unroll
      for (int s = 1; s < 16; s <<= 1) sk = maxu64(sk, shflx64(sk, s));
      const u32 widx = ~(u32)sk;
      cx = xs[widx]; cy = ys[widx]; cz = zs[widx];
      if (tid == 0) {
        float* kb = keyp + ((size_t)b * K + t) * 3;
        kb[0] = cx; kb[1] = cy; kb[2] = cz;
        if ((t & 15) == 15)
          __hip_atomic_store(&progress[b], t, __ATOMIC_RELEASE,
                             __HIP_MEMORY_SCOPE_AGENT);
      }
    }
  } else {
    // ------------------------------ worker ---------------------------------
    const int w = blockIdx.x - 2;
    const int g = tid >> 9, gt = tid & 511;

    for (int p = w; p < nPairs; p += NWORK) {
      const int kp0 = 2 * p;
      const int b = kp0 / K;
      const int tneed = kp0 + 1 - b * K;
      // spin until both keypoints of the pair are published
      for (;;) {
        if (tid == 0)
          readyf = (__hip_atomic_load(&progress[b], __ATOMIC_ACQUIRE,
                                      __HIP_MEMORY_SCOPE_AGENT) >= tneed) ? 1 : 0;
        __syncthreads();
        int rdy = readyf;
        __syncthreads();
        if (rdy) break;
        __builtin_amdgcn_s_sleep(32);
      }

      const float* xs = clouds + (size_t)b * 4 * N;
      const float* ys = xs + N;
      const float* zs = ys + N;
      const float* fs = zs + N;

      for (int m = tid; m < 2048; m += MEGA_T)
        lends[m] = bends[(size_t)b * 2048 + m];
      if (gt == 0) { cnt[g] = 0; bcnt[g] = 0; }
      if (gt < 32) gsort[g][gt] = SENTINEL;
      const int kp = kp0 + g;
      const float kx = keyp[(size_t)kp * 3 + 0];
      const float ky = keyp[(size_t)kp * 3 + 1];
      const float kz = keyp[(size_t)kp * 3 + 2];
      const float bmnx = meta[b * 8 + 0], bmny = meta[b * 8 + 1],
                  bmnz = meta[b * 8 + 2];
      const float csx = meta[b * 8 + 3], csy = meta[b * 8 + 4],
                  csz = meta[b * 8 + 5];
      __syncthreads();

      // bucket culling (per 512-thread group)
      for (int m = gt; m < 2048; m += 512) {
        u32 qx = (m & 1) | ((m >> 2) & 2) | ((m >> 4) & 4) | ((m >> 6) & 8);
        u32 qy = ((m >> 1) & 1) | ((m >> 3) & 2) | ((m >> 5) & 4) | ((m >> 7) & 8);
        u32 qz = ((m >> 2) & 1) | ((m >> 4) & 2) | ((m >> 6) & 4);
        float lx = bmnx + (float)qx * csx - 1e-3f, hx = bmnx + (float)(qx + 1) * csx + 1e-3f;
        float ly = bmny + (float)qy * csy - 1e-3f, hy = bmny + (float)(qy + 1) * csy + 1e-3f;
        float lz = bmnz + (float)qz * csz - 1e-3f, hz = bmnz + (float)(qz + 1) * csz + 1e-3f;
        if (boxlb(kx, ky, kz, lx, hx, ly, hy, lz, hz) < r2b) {
          u32 s = m ? lends[m - 1] : 0u;
          u32 e = lends[m];
          if (e > s) {
            int pos = atomicAdd(&bcnt[g], 1);
            if (pos < BCAP) blist[g][pos] = s | (e << 16);
          }
        }
      }
      __syncthreads();
      const int nb = bcnt[g];
      if (nb <= BCAP) {
        for (int bi = 0; bi < nb; ++bi) {
          u32 pk2 = blist[g][bi];
          u32 s = pk2 & 0xFFFFu, e = pk2 >> 16;
          for (u32 i = s + gt; i < e; i += 512) {
            u32 pi = order[(size_t)b * N + i];
            float dx = __fsub_rn(xs[pi], kx), dy = __fsub_rn(ys[pi], ky),
                  dz = __fsub_rn(zs[pi], kz);
            float d = __fadd_rn(__fadd_rn(__fmul_rn(dx, dx), __fmul_rn(dy, dy)),
                                __fmul_rn(dz, dz));
            if (d < r2b) {
              int pos = atomicAdd(&cnt[g], 1);
              if (pos < CCAP)
                cand[g][pos] = (((u64)__float_as_uint(d)) << 32) | (u64)pi;
            }
          }
        }
      } else {  // sound fallback: full scan (same candidate set)
        for (int i = gt; i < N; i += 512) {
          float dx = __fsub_rn(xs[i], kx), dy = __fsub_rn(ys[i], ky),
                dz = __fsub_rn(zs[i], kz);
          float d = __fadd_rn(__fadd_rn(__fmul_rn(dx, dx), __fmul_rn(dy, dy)),
                              __fmul_rn(dz, dz));
          if (d < r2b) {
            int pos = atomicAdd(&cnt[g], 1);
            if (pos < CCAP)
              cand[g][pos] = (((u64)__float_as_uint(d)) << 32) | (u64)(u32)i;
          }
        }
      }
      __syncthreads();
      const int n = min(cnt[g], CCAP);
      for (int i = gt; i < n; i += 512) {
        u64 kk = cand[g][i];
        int r = 0;
        for (int j = 0; j < n; ++j) r += (cand[g][j] < kk) ? 1 : 0;
        if (r < 32) gsort[g][r] = kk;
      }
      if (gt < 3) out[(size_t)kp * 131 + gt] = keyp[(size_t)kp * 3 + gt];
      __syncthreads();

      // fused pools (whole block, sequential; exact k_pool arithmetic)
      const float k0x = keyp[(size_t)kp0 * 3 + 0];
      const float k0y = keyp[(size_t)kp0 * 3 + 1];
      const float k0z = keyp[(size_t)kp0 * 3 + 2];
      const float k1x = keyp[(size_t)(kp0 + 1) * 3 + 0];
      const float k1y = keyp[(size_t)(kp0 + 1) * 3 + 1];
      const float k1z = keyp[(size_t)(kp0 + 1) * 3 + 2];
      pool_body<16>(tid, kp0, gsort[0], w1a, w2a, r2a, 0, xs, ys, zs, fs,
                    k0x, k0y, k0z, w1l, sgx, sgy, sgz, sgf, h1l, w2l, pm, pooled);
      pool_body<32>(tid, kp0, gsort[0], w1b, w2b, r2b, 256, xs, ys, zs, fs,
                    k0x, k0y, k0z, w1l, sgx, sgy, sgz, sgf, h1l, w2l, pm, pooled);
      pool_body<16>(tid, kp0 + 1, gsort[1], w1a, w2a, r2a, 0, xs, ys, zs, fs,
                    k1x, k1y, k1z, w1l, sgx, sgy, sgz, sgf, h1l, w2l, pm, pooled);
      pool_body<32>(tid, kp0 + 1, gsort[1], w1b, w2b, r2b, 256, xs, ys, zs, fs,
                    k1x, k1y, k1z, w1l, sgx, sgy, sgz, sgf, h1l, w2l, pm, pooled);
    }
  }
}

// ---------------------------------------------------------------------------
// Kernel 4: fuse GEMM [BK,512]@[512,128] + relu -> d_out features (fp32).
// ---------------------------------------------------------------------------
__global__ __launch_bounds__(256) void k_fuse(const float* __restrict__ pooled,
                                              const float* __restrict__ wf,
                                              float* __restrict__ out) {
  const int m0 = blockIdx.x * 16;
  const int tid = threadIdx.x;
  __shared__ float al[16 * 516];
  __shared__ float wl[32 * 128];

  for (int q = tid; q < 16 * 512; q += 256)
    al[(q >> 9) * 516 + (q & 511)] =
        pooled[(size_t)(m0 + (q >> 9)) * 512 + (q & 511)];

  const int rg = tid >> 5;
  const int cg = tid & 31;
  float acc[2][4];
#pragma unroll
  for (int rr = 0; rr < 2; ++rr)
#pragma unroll
    for (int cc = 0; cc < 4; ++cc) acc[rr][cc] = 0.0f;

  for (int kt = 0; kt < 16; ++kt) {
    __syncthreads();
    for (int q = tid; q < 32 * 128; q += 256)
      wl[q] = wf[(size_t)(kt * 32 + (q >> 7)) * 128 + (q & 127)];
    __syncthreads();
    for (int k = 0; k < 32; k += 4) {
      float4 av[2];
#pragma unroll
      for (int rr = 0; rr < 2; ++rr)
        av[rr] = *reinterpret_cast<const float4*>(
            &al[(rg * 2 + rr) * 516 + kt * 32 + k]);
      float4 wv[4];
#pragma unroll
      for (int kk = 0; kk < 4; ++kk)
        wv[kk] = *reinterpret_cast<const float4*>(&wl[(k + kk) * 128 + cg * 4]);
#pragma unroll
      for (int rr = 0; rr < 2; ++rr) {
        const float a0 = av[rr].x, a1 = av[rr].y, a2 = av[rr].z, a3 = av[rr].w;
        acc[rr][0] = fmaf(a3, wv[3].x, fmaf(a2, wv[2].x,
                     fmaf(a1, wv[1].x, fmaf(a0, wv[0].x, acc[rr][0]))));
        acc[rr][1] = fmaf(a3, wv[3].y, fmaf(a2, wv[2].y,
                     fmaf(a1, wv[1].y, fmaf(a0, wv[0].y, acc[rr][1]))));
        acc[rr][2] = fmaf(a3, wv[3].z, fmaf(a2, wv[2].z,
                     fmaf(a1, wv[1].z, fmaf(a0, wv[0].z, acc[rr][2]))));
        acc[rr][3] = fmaf(a3, wv[3].w, fmaf(a2, wv[2].w,
                     fmaf(a1, wv[1].w, fmaf(a0, wv[0].w, acc[rr][3]))));
      }
    }
  }
#pragma unroll
  for (int rr = 0; rr < 2; ++rr) {
    const size_t row = (size_t)(m0 + rg * 2 + rr);
#pragma unroll
    for (int cc = 0; cc < 4; ++cc)
      out[row * 131 + 3 + cg * 4 + cc] = fmaxf(acc[rr][cc], 0.0f);
  }
}

// ---------------------------------------------------------------------------
extern "C" void kernel_launch(void* const* d_in, const int* in_sizes, int n_in,
                              void* d_out, int out_size, void* d_ws, size_t ws_size,
                              hipStream_t stream) {
  const float* clouds = (const float*)d_in[0];
  const float* w1a = (const float*)d_in[1];
  const float* w2a = (const float*)d_in[2];
  const float* w1b = (const float*)d_in[3];
  const float* w2b = (const float*)d_in[4];
  const float* wfu = (const float*)d_in[5];
  float* out = (float*)d_out;

  const int B = 2;
  const int N = in_sizes[0] / (4 * B);  // 16384
  const int K = out_size / (131 * B);   // 4096
  const int BK = B * K;                 // 8192

  char* ws = (char*)d_ws;
  u32* order = (u32*)ws;                                  // B*N u32
  size_t off = ((size_t)B * N * sizeof(u32) + 255) & ~(size_t)255;
  u32* bends = (u32*)(ws + off);                          // B*2048 u32
  off += (size_t)B * 2048 * sizeof(u32);
  off = (off + 255) & ~(size_t)255;
  float* meta = (float*)(ws + off);                       // B*8 f32
  off += (size_t)B * 8 * sizeof(float);
  off = (off + 255) & ~(size_t)255;
  float* keyp = (float*)(ws + off);                       // BK*3 f32
  off += (size_t)BK * 3 * sizeof(float);
  off = (off + 255) & ~(size_t)255;
  int* progress = (int*)(ws + off);                       // B ints
  off += 256;
  float* pooled = (float*)(ws + off);                     // BK*512 f32

  const float r2a = (float)(0.8 * 0.8);
  const float r2b = (float)(1.6 * 1.6);

  k_sort<<<dim3(B), dim3(SORT_T), 0, stream>>>(clouds, order, bends, meta,
                                               progress, N);
  k_mega<<<dim3(2 + NWORK), dim3(MEGA_T), 0, stream>>>(
      clouds, order, bends, meta, w1a, w2a, w1b, w2b, keyp, pooled, out,
      progress, N, K, BK / 2, r2a, r2b);
  k_fuse<<<dim3(BK / 16), dim3(256), 0, stream>>>(pooled, wfu, out);
}

// Round 13
// 5491.201 us; speedup vs baseline: 1.8459x; 1.8459x over previous
//
#include <hip/hip_runtime.h>

typedef unsigned int u32;
typedef unsigned long long u64;
typedef float v2f __attribute__((ext_vector_type(2)));

// ---------------------------------------------------------------------------
// helpers
// ---------------------------------------------------------------------------
__device__ __forceinline__ u64 shflx64(u64 v, int m) {
  int lo = __shfl_xor((int)(u32)v, m, 64);
  int hi = __shfl_xor((int)(u32)(v >> 32), m, 64);
  return ((u64)(u32)hi << 32) | (u32)lo;
}
__device__ __forceinline__ u64 maxu64(u64 a, u64 b) { return a > b ? a : b; }

// squared lower-bound distance from point c to an AABB
__device__ __forceinline__ float boxlb(float cx, float cy, float cz,
                                       float nx, float xx, float ny, float xy,
                                       float nz, float xz) {
  float gx = fmaxf(fmaxf(nx - cx, cx - xx), 0.0f);
  float gy = fmaxf(fmaxf(ny - cy, cy - xy), 0.0f);
  float gz = fmaxf(fmaxf(nz - cz, cz - xz), 0.0f);
  return gx * gx + gy * gy + gz * gz;
}

// ---------------------------------------------------------------------------
// Kernel 0: Morton bucket sort (counting sort, 2048 buckets = 11-bit Morton
// 4/4/3). Also exports per-bucket end offsets + grid metadata so k_knn can
// cull buckets. Within-bucket order is scheduler-dependent -- harmless:
// downstream FPS/knn are exact under any permutation.
// ---------------------------------------------------------------------------
#define SORT_T 1024

__global__ __launch_bounds__(SORT_T) void k_sort(const float* __restrict__ clouds,
                                                 u32* __restrict__ order,
                                                 u32* __restrict__ bends,
                                                 float* __restrict__ meta, int N) {
  const int b = blockIdx.x, tid = threadIdx.x;
  const float* xs = clouds + (size_t)b * 4 * N;
  const float* ys = xs + N;
  const float* zs = ys + N;

  __shared__ u32 hist[2048];
  __shared__ u32 base[2048];
  __shared__ float red[96];
  __shared__ u32 wsum[16];

  // batch bbox
  float mnx = 3.4e38f, mxx = -3.4e38f, mny = 3.4e38f, mxy = -3.4e38f,
        mnz = 3.4e38f, mxz = -3.4e38f;
  for (int i = tid; i < N; i += SORT_T) {
    float x = xs[i], y = ys[i], z = zs[i];
    mnx = fminf(mnx, x); mxx = fmaxf(mxx, x);
    mny = fminf(mny, y); mxy = fmaxf(mxy, y);
    mnz = fminf(mnz, z); mxz = fmaxf(mxz, z);
  }
#pragma unroll
  for (int s = 1; s < 64; s <<= 1) {
    mnx = fminf(mnx, __shfl_xor(mnx, s, 64)); mxx = fmaxf(mxx, __shfl_xor(mxx, s, 64));
    mny = fminf(mny, __shfl_xor(mny, s, 64)); mxy = fmaxf(mxy, __shfl_xor(mxy, s, 64));
    mnz = fminf(mnz, __shfl_xor(mnz, s, 64)); mxz = fmaxf(mxz, __shfl_xor(mxz, s, 64));
  }
  const int wv = tid >> 6, ln = tid & 63;
  if (ln == 0) {
    red[wv * 6 + 0] = mnx; red[wv * 6 + 1] = mxx;
    red[wv * 6 + 2] = mny; red[wv * 6 + 3] = mxy;
    red[wv * 6 + 4] = mnz; red[wv * 6 + 5] = mxz;
  }
  hist[tid] = 0u; hist[tid + 1024] = 0u;
  __syncthreads();
  float bmnx = red[0], bmxx = red[1], bmny = red[2], bmxy = red[3],
        bmnz = red[4], bmxz = red[5];
#pragma unroll
  for (int w = 1; w < 16; ++w) {
    bmnx = fminf(bmnx, red[w * 6 + 0]); bmxx = fmaxf(bmxx, red[w * 6 + 1]);
    bmny = fminf(bmny, red[w * 6 + 2]); bmxy = fmaxf(bmxy, red[w * 6 + 3]);
    bmnz = fminf(bmnz, red[w * 6 + 4]); bmxz = fmaxf(bmxz, red[w * 6 + 5]);
  }
  const float sx = 16.0f / fmaxf(bmxx - bmnx, 1e-9f);
  const float sy = 16.0f / fmaxf(bmxy - bmny, 1e-9f);
  const float sz = 8.0f / fmaxf(bmxz - bmnz, 1e-9f);
  if (tid == 0) {
    meta[b * 8 + 0] = bmnx; meta[b * 8 + 1] = bmny; meta[b * 8 + 2] = bmnz;
    meta[b * 8 + 3] = fmaxf(bmxx - bmnx, 1e-9f) / 16.0f;  // cell sizes (1/s)
    meta[b * 8 + 4] = fmaxf(bmxy - bmny, 1e-9f) / 16.0f;
    meta[b * 8 + 5] = fmaxf(bmxz - bmnz, 1e-9f) / 8.0f;
  }

  // pass 1: histogram
  for (int i = tid; i < N; i += SORT_T) {
    int qx = min(15, max(0, (int)((xs[i] - bmnx) * sx)));
    int qy = min(15, max(0, (int)((ys[i] - bmny) * sy)));
    int qz = min(7, max(0, (int)((zs[i] - bmnz) * sz)));
    u32 m = 0; int sh = 0;
#pragma unroll
    for (int bit = 0; bit < 4; ++bit) {
      m |= ((u32)((qx >> bit) & 1)) << sh++;
      m |= ((u32)((qy >> bit) & 1)) << sh++;
      if (bit < 3) m |= ((u32)((qz >> bit) & 1)) << sh++;
    }
    atomicAdd(&hist[m], 1u);
  }
  __syncthreads();

  // pass 2: exclusive scan (thread owns buckets 2t, 2t+1)
  u32 s0 = hist[2 * tid], s1 = hist[2 * tid + 1];
  u32 ts = s0 + s1;
  u32 x = ts;
#pragma unroll
  for (int d = 1; d < 64; d <<= 1) {
    u32 o = (u32)__shfl_up((int)x, d, 64);
    if (ln >= d) x += o;
  }
  if (ln == 63) wsum[wv] = x;
  __syncthreads();
  u32 wpre = 0;
#pragma unroll
  for (int w = 0; w < 16; ++w) wpre += (w < wv) ? wsum[w] : 0u;
  u32 tbase = wpre + x - ts;
  base[2 * tid] = tbase;
  base[2 * tid + 1] = tbase + s0;
  __syncthreads();

  // pass 3: scatter
  for (int i = tid; i < N; i += SORT_T) {
    int qx = min(15, max(0, (int)((xs[i] - bmnx) * sx)));
    int qy = min(15, max(0, (int)((ys[i] - bmny) * sy)));
    int qz = min(7, max(0, (int)((zs[i] - bmnz) * sz)));
    u32 m = 0; int sh = 0;
#pragma unroll
    for (int bit = 0; bit < 4; ++bit) {
      m |= ((u32)((qx >> bit) & 1)) << sh++;
      m |= ((u32)((qy >> bit) & 1)) << sh++;
      if (bit < 3) m |= ((u32)((qz >> bit) & 1)) << sh++;
    }
    u32 pos = atomicAdd(&base[m], 1u);
    order[(size_t)b * N + pos] = (u32)i;
  }
  __syncthreads();
  // export end offsets (base[m] == end of bucket m after scatter)
  for (int m = tid; m < 2048; m += SORT_T)
    bends[(size_t)b * 2048 + m] = base[m];
}

// ---------------------------------------------------------------------------
// Kernel 1: exact FPS -- the measured optimum (4870/4877 us, reproduced):
// 1024 threads x 16 points, pk fp32 pair update, single barrier per pick.
// Ledger: double-pick, register-tree reduce, LDS coord slots, 512x32 shape,
// and worker-overlap mega-kernel ALL regressed; pk pairs (+1.5%) is the only
// accepted update delta. Per-round serial chain ~2850 cyc x 4095 rounds is
// the structural floor (no pipe saturated; latency-chain-bound on 2 CUs).
// Exactness: pk mul/add with contract(off) rounds RN identically to the
// scalar _rn sequence ((dx^2+dy^2)+dz^2); key = (ddbits<<32)|~orig_idx ==
// numpy argmax-first-occurrence; bbox skips (1e-5 rel margin >> fp32
// rounding) leave dd bitwise identical. All arrays statically indexed
// (scratch-spill rule from round 7).
// ---------------------------------------------------------------------------
#define FPS_T 1024

__global__ __launch_bounds__(FPS_T, 4) void k_fps(const float* __restrict__ clouds,
                                                  const u32* __restrict__ order,
                                                  float* __restrict__ keyp,
                                                  int N, int K) {
  const int b = blockIdx.x, tid = threadIdx.x;
  const float* xs = clouds + (size_t)b * 4 * N;
  const float* ys = xs + N;
  const float* zs = ys + N;

  int oid[16];
  v2f px2[8], py2[8], pz2[8], dd2[8];
#pragma unroll
  for (int j = 0; j < 16; ++j) oid[j] = (int)order[(size_t)b * N + tid * 16 + j];
#pragma unroll
  for (int i = 0; i < 8; ++i) {
    px2[i].x = xs[oid[2 * i]]; px2[i].y = xs[oid[2 * i + 1]];
    py2[i].x = ys[oid[2 * i]]; py2[i].y = ys[oid[2 * i + 1]];
    pz2[i].x = zs[oid[2 * i]]; pz2[i].y = zs[oid[2 * i + 1]];
    dd2[i].x = 1e10f; dd2[i].y = 1e10f;
  }
  // thread bbox
  float bnx = px2[0].x, bxx = px2[0].x, bny = py2[0].x, bxy = py2[0].x,
        bnz = pz2[0].x, bxz = pz2[0].x;
#pragma unroll
  for (int i = 0; i < 8; ++i) {
    bnx = fminf(bnx, fminf(px2[i].x, px2[i].y));
    bxx = fmaxf(bxx, fmaxf(px2[i].x, px2[i].y));
    bny = fminf(bny, fminf(py2[i].x, py2[i].y));
    bxy = fmaxf(bxy, fmaxf(py2[i].x, py2[i].y));
    bnz = fminf(bnz, fminf(pz2[i].x, pz2[i].y));
    bxz = fmaxf(bxz, fmaxf(pz2[i].x, pz2[i].y));
  }
  // wave bbox (butterfly: every lane ends with the wave's bbox)
  float wnx = bnx, wxx = bxx, wny = bny, wxy = bxy, wnz = bnz, wxz = bxz;
#pragma unroll
  for (int s = 1; s < 64; s <<= 1) {
    wnx = fminf(wnx, __shfl_xor(wnx, s, 64)); wxx = fmaxf(wxx, __shfl_xor(wxx, s, 64));
    wny = fminf(wny, __shfl_xor(wny, s, 64)); wxy = fmaxf(wxy, __shfl_xor(wxy, s, 64));
    wnz = fminf(wnz, __shfl_xor(wnz, s, 64)); wxz = fmaxf(wxz, __shfl_xor(wxz, s, 64));
  }

  __shared__ u64 slots[2][16];
  const int wv = tid >> 6, ln = tid & 63;

  u64 ckey = 0, wkey = 0;
  float cmax = 1e10f, wmax = 1e10f;  // 1e10 forces full update at t=1
  float cx = xs[0], cy = ys[0], cz = zs[0];
  if (tid == 0) {
    float* kb = keyp + (size_t)b * K * 3;
    kb[0] = cx; kb[1] = cy; kb[2] = cz;
  }

  for (int t = 1; t < K; ++t) {
    const int par = t & 1;
    // wave-level prune (uniform within wave)
    float gx = fmaxf(fmaxf(wnx - cx, cx - wxx), 0.0f);
    float gy = fmaxf(fmaxf(wny - cy, cy - wxy), 0.0f);
    float gz = fmaxf(fmaxf(wnz - cz, cz - wxz), 0.0f);
    float lbw = gx * gx + gy * gy + gz * gz;
    if (lbw <= wmax * 1.00001f) {
      // thread-level prune
      float hx = fmaxf(fmaxf(bnx - cx, cx - bxx), 0.0f);
      float hy = fmaxf(fmaxf(bny - cy, cy - bxy), 0.0f);
      float hz = fmaxf(fmaxf(bnz - cz, cz - bxz), 0.0f);
      float lbt = hx * hx + hy * hy + hz * hz;
      if (lbt <= cmax * 1.00001f) {
        float m = 0.0f;
        {
#pragma clang fp contract(off)
          const v2f c2x = {cx, cx}, c2y = {cy, cy}, c2z = {cz, cz};
#pragma unroll
          for (int i = 0; i < 8; ++i) {
            v2f dx = px2[i] - c2x;
            v2f dy = py2[i] - c2y;
            v2f dz = pz2[i] - c2z;
            v2f d = (dx * dx + dy * dy) + dz * dz;  // pk mul/add, RN, no fma
            float n0 = fminf(dd2[i].x, d.x);
            float n1 = fminf(dd2[i].y, d.y);
            dd2[i].x = n0; dd2[i].y = n1;
            m = fmaxf(m, fmaxf(n0, n1));
          }
        }
        u32 mi = 0xFFFFFFFFu;
#pragma unroll
        for (int i = 0; i < 8; ++i) {
          if (dd2[i].x == m) mi = min(mi, (u32)oid[2 * i]);
          if (dd2[i].y == m) mi = min(mi, (u32)oid[2 * i + 1]);
        }
        cmax = m;
        ckey = ((u64)__float_as_uint(m) << 32) | (u64)(u32)(~mi);
      }
      u64 wk = ckey;
#pragma unroll
      for (int s = 1; s < 64; s <<= 1) wk = maxu64(wk, shflx64(wk, s));
      wkey = wk;
      wmax = __uint_as_float((u32)(wkey >> 32));
    }
    if (ln == 0) slots[par][wv] = wkey;
    __syncthreads();
    u64 sk = slots[par][ln & 15];
#pragma unroll
    for (int s = 1; s < 16; s <<= 1) sk = maxu64(sk, shflx64(sk, s));
    const u32 widx = ~(u32)sk;
    // broadcast load of winner coords (same address across the wave)
    cx = xs[widx]; cy = ys[widx]; cz = zs[widx];
    if (tid == 0) {
      float* kb = keyp + ((size_t)b * K + t) * 3;
      kb[0] = cx; kb[1] = cy; kb[2] = cz;
    }
  }
}

// ---------------------------------------------------------------------------
// Kernel 2: per-keypoint ball query with Morton-bucket culling. A bucket is
// scanned only if the keypoint's ball can reach its cell AABB (expanded by
// 1e-3 m >> all fp32 quantization/rounding error -- sound cull: any point in
// a culled bucket provably has d2 >= r2b). Candidate SET identical to the
// full scan, so the (d2bits<<32|idx) rank selection output is bitwise
// unchanged. Sentinel = FLT_MAX bits. Writes keypoint coords into d_out.
// ---------------------------------------------------------------------------
#define KNN_T 256
#define KNN_CAP 1024
#define SENTINEL (((u64)0x7F7FFFFFu) << 32)

__global__ __launch_bounds__(KNN_T) void k_knn(const float* __restrict__ clouds,
                                               const float* __restrict__ keyp,
                                               const u32* __restrict__ order,
                                               const u32* __restrict__ bends,
                                               const float* __restrict__ meta,
                                               u64* __restrict__ slots,
                                               float* __restrict__ out,
                                               int N, int K, float r2b) {
  const int kp = blockIdx.x;
  const int b = kp / K;
  const int tid = threadIdx.x;
  const float* xs = clouds + (size_t)b * 4 * N;
  const float* ys = xs + N;
  const float* zs = ys + N;

  __shared__ u64 cand[KNN_CAP];
  __shared__ u32 lends[2048];
  __shared__ u32 blist[2048];  // packed (end<<16)|start
  __shared__ int cnt, bcnt;
  __shared__ u64 sorted32[32];

  if (tid == 0) { cnt = 0; bcnt = 0; }
  if (tid < 32) sorted32[tid] = SENTINEL;
  for (int m = tid; m < 2048; m += KNN_T) lends[m] = bends[(size_t)b * 2048 + m];
  const float kx = keyp[(size_t)kp * 3 + 0];
  const float ky = keyp[(size_t)kp * 3 + 1];
  const float kz = keyp[(size_t)kp * 3 + 2];
  const float bmnx = meta[b * 8 + 0], bmny = meta[b * 8 + 1], bmnz = meta[b * 8 + 2];
  const float csx = meta[b * 8 + 3], csy = meta[b * 8 + 4], csz = meta[b * 8 + 5];
  __syncthreads();

  // stage 1: bucket culling
  for (int m = tid; m < 2048; m += KNN_T) {
    u32 qx = (m & 1) | ((m >> 2) & 2) | ((m >> 4) & 4) | ((m >> 6) & 8);
    u32 qy = ((m >> 1) & 1) | ((m >> 3) & 2) | ((m >> 5) & 4) | ((m >> 7) & 8);
    u32 qz = ((m >> 2) & 1) | ((m >> 4) & 2) | ((m >> 6) & 4);
    float lx = bmnx + (float)qx * csx - 1e-3f, hx = bmnx + (float)(qx + 1) * csx + 1e-3f;
    float ly = bmny + (float)qy * csy - 1e-3f, hy = bmny + (float)(qy + 1) * csy + 1e-3f;
    float lz = bmnz + (float)qz * csz - 1e-3f, hz = bmnz + (float)(qz + 1) * csz + 1e-3f;
    if (boxlb(kx, ky, kz, lx, hx, ly, hy, lz, hz) < r2b) {
      u32 s = m ? lends[m - 1] : 0u;
      u32 e = lends[m];
      if (e > s) {
        int p = atomicAdd(&bcnt, 1);
        blist[p] = s | (e << 16);
      }
    }
  }
  __syncthreads();

  // stage 2: scan surviving buckets only
  const int nb = bcnt;
  for (int bi = 0; bi < nb; ++bi) {
    u32 pk = blist[bi];
    u32 s = pk & 0xFFFFu, e = pk >> 16;
    for (u32 i = s + tid; i < e; i += KNN_T) {
      u32 pi = order[(size_t)b * N + i];
      float dx = __fsub_rn(xs[pi], kx), dy = __fsub_rn(ys[pi], ky),
            dz = __fsub_rn(zs[pi], kz);
      float d = __fadd_rn(__fadd_rn(__fmul_rn(dx, dx), __fmul_rn(dy, dy)),
                          __fmul_rn(dz, dz));
      if (d < r2b) {
        int p = atomicAdd(&cnt, 1);
        if (p < KNN_CAP)
          cand[p] = (((u64)__float_as_uint(d)) << 32) | (u64)pi;
      }
    }
  }
  __syncthreads();
  int n = min(cnt, KNN_CAP);
  for (int i = tid; i < n; i += KNN_T) {
    u64 kk = cand[i];
    int r = 0;
    for (int j = 0; j < n; ++j) r += (cand[j] < kk) ? 1 : 0;
    if (r < 32) sorted32[r] = kk;
  }
  __syncthreads();
  if (tid < 32) slots[(size_t)kp * 32 + tid] = sorted32[tid];
  if (tid < 3) out[(size_t)kp * 131 + tid] = keyp[(size_t)kp * 3 + tid];
}

// ---------------------------------------------------------------------------
// Kernel 3: per-keypoint PointNet layer1 (4->128) + layer2 (128->256) +
// masked max-pool, fp32. One block per keypoint; W2 staged in 32-row k-tiles.
// ---------------------------------------------------------------------------
template <int M>
__global__ __launch_bounds__(256) void k_pool(const float* __restrict__ clouds,
                                              const float* __restrict__ keyp,
                                              const u64* __restrict__ slots,
                                              const float* __restrict__ w1,
                                              const float* __restrict__ w2,
                                              float* __restrict__ pooled,
                                              int N, int K, float R2, int colOff) {
  constexpr int R = M / 4;
  const int kp = blockIdx.x;
  const int b = kp / K;
  const int tid = threadIdx.x;
  const float* xs = clouds + (size_t)b * 4 * N;
  const float* ys = xs + N;
  const float* zs = ys + N;
  const float* fs = zs + N;

  __shared__ float w1l[512];
  __shared__ float gx[32], gy[32], gz[32], gf[32];
  __shared__ float h1l[32 * 132];
  __shared__ float w2l[32 * 256];
  __shared__ u32 pm[256];

  const float kx = keyp[(size_t)kp * 3 + 0];
  const float ky = keyp[(size_t)kp * 3 + 1];
  const float kz = keyp[(size_t)kp * 3 + 2];

  w1l[tid] = w1[tid];
  w1l[tid + 256] = w1[tid + 256];
  pm[tid] = 0u;
  if (tid < M) {
    u64 sl = slots[(size_t)kp * 32 + tid];
    float d2 = __uint_as_float((u32)(sl >> 32));
    u32 idx = (u32)sl;
    float vx = 0.f, vy = 0.f, vz = 0.f, vf = 0.f;
    if (d2 < R2) {
      vx = xs[idx] - kx;
      vy = ys[idx] - ky;
      vz = zs[idx] - kz;
      vf = fs[idx];
    }
    gx[tid] = vx; gy[tid] = vy; gz[tid] = vz; gf[tid] = vf;
  }
  __syncthreads();

  {
    const int c = tid & 127;
#pragma unroll
    for (int p = 0; p < M / 2; ++p) {
      int r = p * 2 + (tid >> 7);
      float h = fmaf(gf[r], w1l[384 + c],
                fmaf(gz[r], w1l[256 + c],
                fmaf(gy[r], w1l[128 + c], gx[r] * w1l[c])));
      h1l[r * 132 + c] = fmaxf(h, 0.0f);
    }
  }

  const int rt = tid >> 6;
  const int cg = tid & 63;
  float acc[R][4];
#pragma unroll
  for (int rr = 0; rr < R; ++rr)
#pragma unroll
    for (int cc = 0; cc < 4; ++cc) acc[rr][cc] = 0.0f;

  for (int kt = 0; kt < 4; ++kt) {
    __syncthreads();
    for (int q = tid; q < 32 * 256; q += 256)
      w2l[q] = w2[(size_t)(kt * 32 + (q >> 8)) * 256 + (q & 255)];
    __syncthreads();
    for (int k = 0; k < 32; k += 4) {
      float4 hv[R];
#pragma unroll
      for (int rr = 0; rr < R; ++rr)
        hv[rr] = *reinterpret_cast<const float4*>(
            &h1l[(rt * R + rr) * 132 + kt * 32 + k]);
      float4 wv[4];
#pragma unroll
      for (int kk = 0; kk < 4; ++kk)
        wv[kk] = *reinterpret_cast<const float4*>(
            &w2l[(k + kk) * 256 + cg * 4]);
#pragma unroll
      for (int rr = 0; rr < R; ++rr) {
        const float a0 = hv[rr].x, a1 = hv[rr].y, a2 = hv[rr].z, a3 = hv[rr].w;
        acc[rr][0] = fmaf(a3, wv[3].x, fmaf(a2, wv[2].x,
                     fmaf(a1, wv[1].x, fmaf(a0, wv[0].x, acc[rr][0]))));
        acc[rr][1] = fmaf(a3, wv[3].y, fmaf(a2, wv[2].y,
                     fmaf(a1, wv[1].y, fmaf(a0, wv[0].y, acc[rr][1]))));
        acc[rr][2] = fmaf(a3, wv[3].z, fmaf(a2, wv[2].z,
                     fmaf(a1, wv[1].z, fmaf(a0, wv[0].z, acc[rr][2]))));
        acc[rr][3] = fmaf(a3, wv[3].w, fmaf(a2, wv[2].w,
                     fmaf(a1, wv[1].w, fmaf(a0, wv[0].w, acc[rr][3]))));
      }
    }
  }
#pragma unroll
  for (int cc = 0; cc < 4; ++cc) {
    float mx = 0.0f;
#pragma unroll
    for (int rr = 0; rr < R; ++rr) mx = fmaxf(mx, acc[rr][cc]);
    atomicMax(&pm[cg * 4 + cc], __float_as_uint(mx));
  }
  __syncthreads();
  pooled[(size_t)kp * 512 + colOff + tid] = __uint_as_float(pm[tid]);
}

// ---------------------------------------------------------------------------
// Kernel 4: fuse GEMM [BK,512]@[512,128] + relu -> d_out features (fp32).
// ---------------------------------------------------------------------------
__global__ __launch_bounds__(256) void k_fuse(const float* __restrict__ pooled,
                                              const float* __restrict__ wf,
                                              float* __restrict__ out) {
  const int m0 = blockIdx.x * 16;
  const int tid = threadIdx.x;
  __shared__ float al[16 * 516];
  __shared__ float wl[32 * 128];

  for (int q = tid; q < 16 * 512; q += 256)
    al[(q >> 9) * 516 + (q & 511)] =
        pooled[(size_t)(m0 + (q >> 9)) * 512 + (q & 511)];

  const int rg = tid >> 5;
  const int cg = tid & 31;
  float acc[2][4];
#pragma unroll
  for (int rr = 0; rr < 2; ++rr)
#pragma unroll
    for (int cc = 0; cc < 4; ++cc) acc[rr][cc] = 0.0f;

  for (int kt = 0; kt < 16; ++kt) {
    __syncthreads();
    for (int q = tid; q < 32 * 128; q += 256)
      wl[q] = wf[(size_t)(kt * 32 + (q >> 7)) * 128 + (q & 127)];
    __syncthreads();
    for (int k = 0; k < 32; k += 4) {
      float4 av[2];
#pragma unroll
      for (int rr = 0; rr < 2; ++rr)
        av[rr] = *reinterpret_cast<const float4*>(
            &al[(rg * 2 + rr) * 516 + kt * 32 + k]);
      float4 wv[4];
#pragma unroll
      for (int kk = 0; kk < 4; ++kk)
        wv[kk] = *reinterpret_cast<const float4*>(&wl[(k + kk) * 128 + cg * 4]);
#pragma unroll
      for (int rr = 0; rr < 2; ++rr) {
        const float a0 = av[rr].x, a1 = av[rr].y, a2 = av[rr].z, a3 = av[rr].w;
        acc[rr][0] = fmaf(a3, wv[3].x, fmaf(a2, wv[2].x,
                     fmaf(a1, wv[1].x, fmaf(a0, wv[0].x, acc[rr][0]))));
        acc[rr][1] = fmaf(a3, wv[3].y, fmaf(a2, wv[2].y,
                     fmaf(a1, wv[1].y, fmaf(a0, wv[0].y, acc[rr][1]))));
        acc[rr][2] = fmaf(a3, wv[3].z, fmaf(a2, wv[2].z,
                     fmaf(a1, wv[1].z, fmaf(a0, wv[0].z, acc[rr][2]))));
        acc[rr][3] = fmaf(a3, wv[3].w, fmaf(a2, wv[2].w,
                     fmaf(a1, wv[1].w, fmaf(a0, wv[0].w, acc[rr][3]))));
      }
    }
  }
#pragma unroll
  for (int rr = 0; rr < 2; ++rr) {
    const size_t row = (size_t)(m0 + rg * 2 + rr);
#pragma unroll
    for (int cc = 0; cc < 4; ++cc)
      out[row * 131 + 3 + cg * 4 + cc] = fmaxf(acc[rr][cc], 0.0f);
  }
}

// ---------------------------------------------------------------------------
extern "C" void kernel_launch(void* const* d_in, const int* in_sizes, int n_in,
                              void* d_out, int out_size, void* d_ws, size_t ws_size,
                              hipStream_t stream) {
  const float* clouds = (const float*)d_in[0];
  const float* w1a = (const float*)d_in[1];
  const float* w2a = (const float*)d_in[2];
  const float* w1b = (const float*)d_in[3];
  const float* w2b = (const float*)d_in[4];
  const float* wfu = (const float*)d_in[5];
  float* out = (float*)d_out;

  const int B = 2;
  const int N = in_sizes[0] / (4 * B);  // 16384
  const int K = out_size / (131 * B);   // 4096
  const int BK = B * K;                 // 8192

  char* ws = (char*)d_ws;
  u32* order = (u32*)ws;                                  // B*N u32
  size_t off = ((size_t)B * N * sizeof(u32) + 255) & ~(size_t)255;
  u32* bends = (u32*)(ws + off);                          // B*2048 u32
  off += (size_t)B * 2048 * sizeof(u32);
  off = (off + 255) & ~(size_t)255;
  float* meta = (float*)(ws + off);                       // B*8 f32
  off += (size_t)B * 8 * sizeof(float);
  off = (off + 255) & ~(size_t)255;
  float* keyp = (float*)(ws + off);                       // BK*3 f32
  off += (size_t)BK * 3 * sizeof(float);
  off = (off + 255) & ~(size_t)255;
  u64* slots = (u64*)(ws + off);                          // BK*32 u64
  off += (size_t)BK * 32 * sizeof(u64);
  off = (off + 255) & ~(size_t)255;
  float* pooled = (float*)(ws + off);                     // BK*512 f32

  const float r2a = (float)(0.8 * 0.8);
  const float r2b = (float)(1.6 * 1.6);

  k_sort<<<dim3(B), dim3(SORT_T), 0, stream>>>(clouds, order, bends, meta, N);
  k_fps<<<dim3(B), dim3(FPS_T), 0, stream>>>(clouds, order, keyp, N, K);
  k_knn<<<dim3(BK), dim3(KNN_T), 0, stream>>>(clouds, keyp, order, bends, meta,
                                              slots, out, N, K, r2b);
  k_pool<16><<<dim3(BK), dim3(256), 0, stream>>>(clouds, keyp, slots, w1a, w2a,
                                                 pooled, N, K, r2a, 0);
  k_pool<32><<<dim3(BK), dim3(256), 0, stream>>>(clouds, keyp, slots, w1b, w2b,
                                                 pooled, N, K, r2b, 256);
  k_fuse<<<dim3(BK / 16), dim3(256), 0, stream>>>(pooled, wfu, out);
}